// Round 8
// baseline (1996.394 us; speedup 1.0000x reference)
//
#include <hip/hip_runtime.h>
#include <cstdint>
#include <cstddef>
#include <math.h>

#define NANCH    36864
#define NPRE     12000
#define NPRE_PAD 12032
#define NW       188
#define NPOST    2000

// triangle base for chunk-pair (ci, cj>=ci): slot = tribase(ci) + (cj-ci)
__device__ __forceinline__ int tribase(int ci) { return ci * NW - (ci * (ci - 1)) / 2; }

// ---------------------------------------------------------------------------
// K1a: K-split 3x3 conv half (512 ic), f64 partial accumulate, NO bias/relu.
// [R5-R7: ~950us, VALU 73%] — unchanged (control).
// ---------------------------------------------------------------------------
__global__ __launch_bounds__(256, 2)
void k_conv_ks(const float* __restrict__ xg, const float* __restrict__ wg_,
               double* __restrict__ p0g, double* __restrict__ p1g)
{
    __shared__ float wlds[144 * 64];     // 36 KB
    __shared__ float xlds[16 * 4 * 76];  // 19 KB
    const int tid = threadIdx.x;
    const int ks  = blockIdx.x >> 8;
    const int inner = blockIdx.x & 255;
    const int oct = inner & 7;
    const int rp  = inner >> 3;
    const int oc0 = oct << 6;
    const int y0  = rp << 1;
    const int ocg = tid >> 4;
    const int pxg = tid & 15;
    const int ry  = pxg >> 3;
    const int cx0 = (pxg & 7) << 3;
    const int lane = tid & 63, wv = tid >> 6;
    const int icbase = ks << 9;

    double acc[4][8];
#pragma unroll
    for (int o = 0; o < 4; ++o)
#pragma unroll
        for (int j = 0; j < 8; ++j) acc[o][j] = 0.0;

    int xoff[17], loff[17];
#pragma unroll
    for (int t = 0; t < 17; ++t) {
        int f = tid + 256 * t;
        if (f < 4224) {
            int ic = f / 264; int r = f - ic * 264; int srow = r / 66; int gc = r - srow * 66;
            loff[t] = (ic * 4 + srow) * 76 + gc;
            int gy = y0 + srow - 1, gx = gc - 1;
            xoff[t] = (gy >= 0 && gy < 64 && gx >= 0 && gx < 64)
                      ? (ic * 4096 + gy * 64 + gx) : -1;
        } else { loff[t] = -1; xoff[t] = -1; }
    }

    const float* wbase = wg_ + (size_t)(oc0 + lane) * 9216 + (size_t)icbase * 9 + wv;
    const float* xbase = xg + (size_t)icbase * 4096;
    float wreg[36], xreg[17];

#pragma unroll
    for (int t = 0; t < 36; ++t) wreg[t] = wbase[4 * t];
#pragma unroll
    for (int t = 0; t < 17; ++t) xreg[t] = (xoff[t] >= 0) ? xbase[xoff[t]] : 0.f;

    for (int kc = 0; kc < 32; ++kc) {
        __syncthreads();
#pragma unroll
        for (int t = 0; t < 36; ++t) wlds[(wv + 4 * t) * 64 + lane] = wreg[t];
#pragma unroll
        for (int t = 0; t < 17; ++t)
            if (loff[t] >= 0) xlds[loff[t]] = xreg[t];
        if (kc < 31) {
            const float* wp = wbase + (kc + 1) * 144;
            const float* xp = xbase + (size_t)(kc + 1) * 16 * 4096;
#pragma unroll
            for (int t = 0; t < 36; ++t) wreg[t] = wp[4 * t];
#pragma unroll
            for (int t = 0; t < 17; ++t) xreg[t] = (xoff[t] >= 0) ? xp[xoff[t]] : 0.f;
        }
        __syncthreads();
#pragma unroll 1
        for (int ic = 0; ic < 16; ++ic) {
#pragma unroll
            for (int ky = 0; ky < 3; ++ky) {
                const float* xr = &xlds[(ic * 4 + ry + ky) * 76 + cx0];
                float4 t0 = *(const float4*)(xr);
                float4 t1 = *(const float4*)(xr + 4);
                float2 t2 = *(const float2*)(xr + 8);
                double xwd[10] = {t0.x, t0.y, t0.z, t0.w, t1.x, t1.y, t1.z, t1.w, t2.x, t2.y};
#pragma unroll
                for (int kx = 0; kx < 3; ++kx) {
                    const float4 wq = *(const float4*)&wlds[(ic * 9 + ky * 3 + kx) * 64 + (ocg << 2)];
                    double wdv[4] = {wq.x, wq.y, wq.z, wq.w};
#pragma unroll
                    for (int o = 0; o < 4; ++o)
#pragma unroll
                        for (int j = 0; j < 8; ++j)
                            acc[o][j] = fma(wdv[o], xwd[j + kx], acc[o][j]);
                }
            }
        }
    }
    double* pg = ks ? p1g : p0g;
#pragma unroll
    for (int o = 0; o < 4; ++o) {
        const int oc = oc0 + (ocg << 2) + o;
        double* pp = pg + (size_t)oc * 4096 + (y0 + ry) * 64 + cx0;
#pragma unroll
        for (int j = 0; j < 8; j += 2)
            *(double2*)(pp + j) = make_double2(acc[o][j], acc[o][j + 1]);
    }
}

// ---------------------------------------------------------------------------
// K2: fused combine + 1x1 heads. Reads P0+P1+bias directly (k_comb deleted;
// saves a dispatch + the 16.8MB h round-trip). Numerically identical: f64
// sum -> leaky -> f32 cast, then f64-accumulated 1x1 conv on the f32 values.
// Block 0 also inits suppr (k_rank atomicOrs into it later).
// ---------------------------------------------------------------------------
__global__ __launch_bounds__(256, 1)
void k_heads_f(const double* __restrict__ P0, const double* __restrict__ P1,
               const float* __restrict__ conv_b,
               const float* __restrict__ loc_w, const float* __restrict__ loc_b,
               const float* __restrict__ score_w, const float* __restrict__ score_b,
               const int* __restrict__ imh, const int* __restrict__ imw,
               float* __restrict__ out, float* __restrict__ boxes_all,
               unsigned long long* __restrict__ keys64,
               unsigned long long* __restrict__ suppr)
{
    __shared__ float  hch[64 * 64];
    __shared__ float  wch[54 * 64];
    __shared__ float  ol[54 * 64];
    __shared__ double sld[18 * 64];
    const int y = blockIdx.x, tid = threadIdx.x;
    const int px = tid & 63, cg = tid >> 6;
    double acc[14];
#pragma unroll
    for (int u = 0; u < 14; ++u) acc[u] = 0.0;
    for (int cc = 0; cc < 8; ++cc) {
        __syncthreads();
#pragma unroll
        for (int t = 0; t < 16; ++t) {
            int f = tid + 256 * t;
            int ch = cc * 64 + (f >> 6);
            size_t gi = (size_t)ch * 4096 + y * 64 + (f & 63);
            double v = P0[gi] + P1[gi] + (double)conv_b[ch];
            hch[f] = (float)((v >= 0.0) ? v : 0.01 * v);
        }
#pragma unroll
        for (int t = 0; t < 14; ++t) {
            int f = tid + 256 * t;
            if (f < 54 * 64) {
                int ch = f >> 6, c = f & 63;
                wch[f] = (ch < 36) ? loc_w[ch * 512 + cc * 64 + c]
                                   : score_w[(ch - 36) * 512 + cc * 64 + c];
            }
        }
        __syncthreads();
        for (int c = 0; c < 64; ++c) {
            double hvd = (double)hch[c * 64 + px];
#pragma unroll
            for (int u = 0; u < 14; ++u) {
                int ch = cg + 4 * u;
                if (ch < 54) acc[u] = fma((double)wch[ch * 64 + c], hvd, acc[u]);
            }
        }
    }
    __syncthreads();
#pragma unroll
    for (int u = 0; u < 14; ++u) {
        int ch = cg + 4 * u;
        if (ch < 54) {
            double s = acc[u] + (double)((ch < 36) ? loc_b[ch] : score_b[ch - 36]);
            ol[ch * 64 + px] = (float)s;
            if (ch >= 36) sld[(ch - 36) * 64 + px] = s;
        }
    }
    __syncthreads();
    for (int f = tid; f < 64 * 36; f += 256) {
        int p = f / 36, ch = f - 36 * p;
        out[(size_t)(y * 64 + p) * 36 + ch] = ol[ch * 64 + p];
    }
    for (int f = tid; f < 64 * 18; f += 256) {
        int p = f / 18, ch = f - 18 * p;
        out[147456 + (size_t)(y * 64 + p) * 18 + ch] = ol[(36 + ch) * 64 + p];
    }
    const float fy = (float)(*imh), fx = (float)(*imw);
    float* anch = out + 229184;
    for (int t2 = tid; t2 < 576; t2 += 256) {
        int p = t2 / 9, a = t2 - 9 * p;
        int pg = y * 64 + p;
        int ar = a / 3, as = a - 3 * ar;
        double rr = (ar == 0) ? 0.5 : ((ar == 1) ? 1.0 : 2.0);
        double ss = (as == 0) ? 8.0 : ((as == 1) ? 16.0 : 32.0);
        double hh = 16.0 * ss * sqrt(rr), wwd = 16.0 * ss * sqrt(1.0 / rr);
        float by1 = (float)(8.0 - hh * 0.5), bx1 = (float)(8.0 - wwd * 0.5);
        float by2 = (float)(8.0 + hh * 0.5), bx2 = (float)(8.0 + wwd * 0.5);
        float sy = (float)(y * 16), sx = (float)(p * 16);
        float a0 = sy + by1, a1 = sx + bx1, a2 = sy + by2, a3 = sx + bx2;
        int base = (pg * 9 + a) * 4;
        anch[base + 0] = a0; anch[base + 1] = a1; anch[base + 2] = a2; anch[base + 3] = a3;
        double d = sld[(a * 2 + 1) * 64 + p] - sld[(a * 2) * 64 + p];
        long long bits = __double_as_longlong(d);
        unsigned long long u64 =
            (unsigned long long)(bits ^ ((bits >> 63) | (long long)0x8000000000000000LL));
        unsigned long long v = ~u64;  // ascending v == descending fg
        keys64[pg * 9 + a] = (v & 0xFFFFFFFFFFFF0000ULL) | (unsigned long long)(pg * 9 + a);
        float dy = ol[(a * 4 + 0) * 64 + p], dxv = ol[(a * 4 + 1) * 64 + p];
        float dh = ol[(a * 4 + 2) * 64 + p], dwv = ol[(a * 4 + 3) * 64 + p];
        float hA = a2 - a0, wA = a3 - a1;
        float cya = a0 + 0.5f * hA, cxa = a1 + 0.5f * wA;
        float cy = dy * hA + cya, cx = dxv * wA + cxa;
        float hb = hA * expf(dh), wb = wA * expf(dwv);
        float b0 = fminf(fmaxf(cy - 0.5f * hb, 0.f), fy);
        float b1 = fminf(fmaxf(cx - 0.5f * wb, 0.f), fx);
        float b2 = fminf(fmaxf(cy + 0.5f * hb, 0.f), fy);
        float b3 = fminf(fmaxf(cx + 0.5f * wb, 0.f), fx);
        boxes_all[base + 0] = b0; boxes_all[base + 1] = b1;
        boxes_all[base + 2] = b2; boxes_all[base + 3] = b3;
    }
    // init suppr for k_rank (runs strictly before in stream order)
    if (blockIdx.x == 0 && tid < NW)
        suppr[tid] = (tid == NW - 1) ? 0xFFFFFFFF00000000ULL : 0ULL;
}

// ---------------------------------------------------------------------------
// K3 (replaces single-block radix+bitonic k_select): RANK BY COUNTING.
// Keys are unique (48-bit score | 16-bit idx) => rank(i) = #{j: key_j<key_i}
// is an exact permutation; ranks<12000 == argsort[:12000] with stable ties.
// O(n^2)=1.36G u64-compares but fully parallel (576 waves, zero barriers-
// serial structure) vs R7's 345-barrier single-CU bitonic. Scatter fused:
// each thread knows its final rank. 144 blocks x 256 thr.
// ---------------------------------------------------------------------------
__global__ __launch_bounds__(256, 1)
void k_rank(const unsigned long long* __restrict__ keys64,
            const float* __restrict__ boxes_all,
            float* __restrict__ sbox, float* __restrict__ areas,
            unsigned long long* __restrict__ suppr)
{
    __shared__ unsigned long long kch[2048];   // 16 KB
    const int tid = threadIdx.x;
    const int i = blockIdx.x * 256 + tid;      // 144*256 == 36864 exactly
    const unsigned long long mykey = keys64[i];
    int cnt = 0;
    for (int c0 = 0; c0 < NANCH; c0 += 2048) {
        __syncthreads();
#pragma unroll
        for (int t = 0; t < 8; ++t) kch[tid + 256 * t] = keys64[c0 + tid + 256 * t];
        __syncthreads();
        const ulonglong2* k2 = (const ulonglong2*)kch;
#pragma unroll 8
        for (int jj = 0; jj < 1024; ++jj) {
            ulonglong2 kk = k2[jj];
            cnt += (kk.x < mykey) ? 1 : 0;
            cnt += (kk.y < mykey) ? 1 : 0;
        }
    }
    if (cnt < NPRE) {
        const float* bp = boxes_all + (size_t)i * 4;
        float b0 = bp[0], b1 = bp[1], b2 = bp[2], b3 = bp[3];
        sbox[cnt * 4 + 0] = b0; sbox[cnt * 4 + 1] = b1;
        sbox[cnt * 4 + 2] = b2; sbox[cnt * 4 + 3] = b3;
        areas[cnt] = (b2 - b0) * (b3 - b1);
        bool valid = ((b2 - b0) >= 16.0f) && ((b3 - b1) >= 16.0f);
        if (!valid) atomicOr(&suppr[cnt >> 6], 1ULL << (cnt & 63));
    }
    // zero pad rows 12000..12031 (marked suppressed via suppr word 187 init)
    if (blockIdx.x == 0 && tid < 32) {
        int r = NPRE + tid;
        sbox[r * 4 + 0] = 0.f; sbox[r * 4 + 1] = 0.f;
        sbox[r * 4 + 2] = 0.f; sbox[r * 4 + 3] = 0.f;
        areas[r] = 0.f;
    }
}

// ---------------------------------------------------------------------------
// K4: pairwise IoU bit mask, upper-triangle layout (R5/R7 version, unchanged).
// ---------------------------------------------------------------------------
__global__ __launch_bounds__(256, 1)
void k_mask(const float* __restrict__ sbox, const float* __restrict__ areas,
            unsigned long long* __restrict__ mask)
{
    const int cj = blockIdx.x, q = blockIdx.y;
    __shared__ float4 bx[64];
    __shared__ float aj[64];
    const int t = threadIdx.x;
    const int j0 = cj * 64;
    if (t < 64) { bx[t] = ((const float4*)sbox)[j0 + t]; aj[t] = areas[j0 + t]; }
    __syncthreads();
    const int c0 = ((cj + 1) * q) >> 2, c1 = ((cj + 1) * (q + 1)) >> 2;
    for (int i0 = c0 * 64; i0 < c1 * 64; i0 += 256) {
        int i = i0 + t;
        if (i < c1 * 64) {
            const float4 p = ((const float4*)sbox)[i];
            const float ai = areas[i];
            unsigned long long w = 0;
            for (int jj = 0; jj < 64; ++jj) {
                float4 qb = bx[jj];
                float yy1 = fmaxf(p.x, qb.x), xx1 = fmaxf(p.y, qb.y);
                float yy2 = fminf(p.z, qb.z), xx2 = fminf(p.w, qb.w);
                float inter = fmaxf(yy2 - yy1, 0.f) * fmaxf(xx2 - xx1, 0.f);
                float iou = inter / (ai + aj[jj] - inter + 1e-10f);
                w |= ((unsigned long long)((iou > 0.7f) && (j0 + jj > i))) << jj;
            }
            int ci = i >> 6;
            mask[(size_t)(tribase(ci) + (cj - ci)) * 64 + (i & 63)] = w;
        }
    }
}

// ---------------------------------------------------------------------------
// K5: sequential greedy scan (R5/R7 version, unchanged).
// ---------------------------------------------------------------------------
__global__ __launch_bounds__(256, 1)
void k_scan(const unsigned long long* __restrict__ mask,
            const unsigned long long* __restrict__ suppr,
            const float* __restrict__ sbox, float* __restrict__ rois)
{
    __shared__ unsigned long long rvs[NW];
    __shared__ unsigned long long curw;
    __shared__ unsigned long long keptw[NW];
    __shared__ int totkept, brk;
    __shared__ int pref[NW + 1];
    const int tid = threadIdx.x;
    if (tid < NW) { rvs[tid] = suppr[tid]; keptw[tid] = 0ULL; }
    if (tid == 0) { totkept = 0; brk = 0; }
    __syncthreads();
    for (int c = 0; c < NW; ++c) {
        if (tid < 64) {
            unsigned long long diag = mask[(size_t)tribase(c) * 64 + tid];
            unsigned long long w = rvs[c];
            for (int b = 0; b < 64; ++b) {
                unsigned long long db = __shfl(diag, b, 64);
                if (!((w >> b) & 1ULL)) w |= db;
            }
            if (tid == 0) {
                curw = w;
                keptw[c] = ~w;
                totkept += __popcll(~w);
                if (totkept >= NPOST) brk = 1;
            }
        }
        __syncthreads();
        if (brk) break;
        unsigned long long kw = ~curw;
        if (kw && tid > c && tid < NW) {
            const unsigned long long* mrow = mask + (size_t)(tribase(c) + (tid - c)) * 64;
            unsigned long long a0 = 0, a1 = 0, a2 = 0, a3 = 0;
            for (int b = 0; b < 64; b += 4) {
                unsigned long long m0 = mrow[b + 0];
                unsigned long long m1 = mrow[b + 1];
                unsigned long long m2 = mrow[b + 2];
                unsigned long long m3 = mrow[b + 3];
                if ((kw >> (b + 0)) & 1ULL) a0 |= m0;
                if ((kw >> (b + 1)) & 1ULL) a1 |= m1;
                if ((kw >> (b + 2)) & 1ULL) a2 |= m2;
                if ((kw >> (b + 3)) & 1ULL) a3 |= m3;
            }
            rvs[tid] |= a0 | a1 | a2 | a3;
        }
        __syncthreads();
    }
    __syncthreads();
    if (tid == 0) {
        int s = 0;
        for (int c = 0; c < NW; ++c) { pref[c] = s; s += __popcll(keptw[c]); }
        pref[NW] = s;
    }
    __syncthreads();
    int total = pref[NW]; if (total > NPOST) total = NPOST;
    for (int r = total * 4 + tid; r < NPOST * 4; r += 256) rois[r] = 0.f;
    if (tid < NW) {
        unsigned long long kw = keptw[tid];
        int r = pref[tid];
        for (int b = 0; b < 64; ++b) {
            if ((kw >> b) & 1ULL) {
                if (r < NPOST) {
                    const float* bp = sbox + (size_t)(tid * 64 + b) * 4;
                    rois[r * 4 + 0] = bp[0]; rois[r * 4 + 1] = bp[1];
                    rois[r * 4 + 2] = bp[2]; rois[r * 4 + 3] = bp[3];
                }
                ++r;
            }
        }
    }
}

// ---------------------------------------------------------------------------
extern "C" void kernel_launch(void* const* d_in, const int* in_sizes, int n_in,
                              void* d_out, int out_size, void* d_ws, size_t ws_size,
                              hipStream_t stream)
{
    const float* x       = (const float*)d_in[0];
    const float* conv_w  = (const float*)d_in[1];
    const float* conv_b  = (const float*)d_in[2];
    const float* score_w = (const float*)d_in[3];
    const float* score_b = (const float*)d_in[4];
    const float* loc_w   = (const float*)d_in[5];
    const float* loc_b   = (const float*)d_in[6];
    const int*   imh     = (const int*)d_in[7];
    const int*   imw     = (const int*)d_in[8];
    float* out = (float*)d_out;
    char* ws = (char*)d_ws;
    // layout: [ (unused 8.4MB) ][P0 16.8MB][P1 16.8MB]; tail buffers overlay
    // the low region + P0/P1 are read by k_heads_f then dead. 40MB total.
    double* P0                  = (double*)(ws + 8388608);              // 16777216
    double* P1                  = (double*)(ws + 25165824);             // 16777216
    float* boxes_all            = (float*)(ws);                         // 589824
    unsigned long long* keys64  = (unsigned long long*)(ws + 589824);   // 294912
    float* sbox                 = (float*)(ws + 884736);                // 192512
    float* areas                = (float*)(ws + 1077248);               // 48128
    unsigned long long* suppr   = (unsigned long long*)(ws + 1125376);  // 1536
    unsigned long long* mask    = (unsigned long long*)(ws + 1126912);  // 9096192 (triangle)

    k_conv_ks<<<512, 256, 0, stream>>>(x, conv_w, P0, P1);
    k_heads_f<<<64, 256, 0, stream>>>(P0, P1, conv_b, loc_w, loc_b, score_w,
                                      score_b, imh, imw, out, boxes_all,
                                      keys64, suppr);
    k_rank   <<<144, 256, 0, stream>>>(keys64, boxes_all, sbox, areas, suppr);
    k_mask   <<<dim3(188, 4), 256, 0, stream>>>(sbox, areas, mask);
    k_scan   <<<1, 256, 0, stream>>>(mask, suppr, sbox, out + 221184);
}